// Round 8
// baseline (318.668 us; speedup 1.0000x reference)
//
#include <hip/hip_runtime.h>
#include <math.h>

#define HEADS 4
#define BATCH 8
#define SEQ   1024
#define CH    256
#define DH    64
#define RB    16          // q rows per block
#define NTHR  512         // 8 waves
#define SSTR  1032        // Sraw row stride in u16 (2064 B, 16B-mult)
#define PSTR  132         // pre row stride in u16 (264 B): bank-partitioned reads

typedef float  floatx4  __attribute__((ext_vector_type(4)));
typedef short  shortx8  __attribute__((ext_vector_type(8)));
typedef unsigned short ushortx4 __attribute__((ext_vector_type(4)));

__device__ __forceinline__ unsigned short f2bf(float f) {
    unsigned u = __float_as_uint(f);
    unsigned r = u + 0x7FFFu + ((u >> 16) & 1u);   // RNE
    return (unsigned short)(r >> 16);
}
__device__ __forceinline__ float bf2f(unsigned short h) {
    return __uint_as_float(((unsigned)h) << 16);
}
__device__ __forceinline__ shortx8 pack8(float4 a, float4 b) {
    shortx8 r;
    r[0] = (short)f2bf(a.x); r[1] = (short)f2bf(a.y);
    r[2] = (short)f2bf(a.z); r[3] = (short)f2bf(a.w);
    r[4] = (short)f2bf(b.x); r[5] = (short)f2bf(b.y);
    r[6] = (short)f2bf(b.z); r[7] = (short)f2bf(b.w);
    return r;
}

__global__ __launch_bounds__(NTHR, 6)
void attn_mfma(const float* __restrict__ q, const float* __restrict__ k,
               const float* __restrict__ v, const void* __restrict__ maskp,
               const float* __restrict__ dis, float* __restrict__ out,
               float* __restrict__ pout)
{
    __shared__ unsigned short Sraw[RB][SSTR];     // 33 KB: exp(score) bf16
    __shared__ unsigned short pre[2][RB][PSTR];   // 8.4 KB dbuf pre-scores
    __shared__ float Opart[RB][65];               // 4.2 KB partial O
    __shared__ float part[8][RB];                 // per-wave row partials
    __shared__ float invs[RB];

    const int t   = threadIdx.x;
    const int bid = blockIdx.x;
    const int nb  = bid & 63;          // 64 row-tiles per (h,b)
    const int hb  = bid >> 6;
    const int b   = hb & (BATCH - 1);
    const int h   = hb >> 3;
    const int n0  = nb * RB;

    const int lane = t & 63;
    const int w    = t >> 6;       // wave 0..7
    const int ln   = lane & 15;    // fragment m / n index
    const int qd   = lane >> 4;    // quad -> k-group / D row group

    // loader mapping for dis/mask chunks: 16 rows x 128 cols per chunk
    const int lr = t >> 5;         // row 0..15
    const int lc = t & 31;         // col-quad 0..31

    // ---- inline mask-dtype detect: int32 bool => high bytes of words all 0.
    int fl;
    {
        const unsigned* mw = (const unsigned*)maskp;
        int found = 0;
        #pragma unroll
        for (int j = 0; j < 16; ++j)
            if (mw[lane * 16 + j] & 0xFFFFFF00u) found = 1;
        fl = (__ballot(found != 0) != 0ULL) ? 1 : 0;   // 1 => byte mask
    }
    const unsigned char* mask8  = (const unsigned char*)maskp;
    const int*           mask32 = (const int*)maskp;

    const float* disrow = dis + ((size_t)(b * SEQ + n0 + lr)) * SEQ;
    const unsigned char* m8r  = mask8  + ((size_t)(b * SEQ + n0 + lr)) * SEQ;
    const int*           m32r = mask32 + ((size_t)(b * SEQ + n0 + lr)) * SEQ;

    // ---- Q A-frags straight from global ----
    const float* qrow = q + ((size_t)(b * SEQ + n0 + ln)) * CH + h * DH;
    shortx8 aq0, aq1;
    {
        float4 a0 = *(const float4*)(qrow + qd * 8);
        float4 a1 = *(const float4*)(qrow + qd * 8 + 4);
        float4 a2 = *(const float4*)(qrow + 32 + qd * 8);
        float4 a3 = *(const float4*)(qrow + 32 + qd * 8 + 4);
        aq0 = pack8(a0, a1);
        aq1 = pack8(a2, a3);
    }

    // ---- preload chunk 0 dis/mask, stage into pre[0] ----
    {
        float4 pd = *(const float4*)(disrow + lc * 4);
        unsigned mkb;
        if (fl) {
            mkb = *(const unsigned*)(m8r + lc * 4);
        } else {
            int4 mv = *(const int4*)(m32r + lc * 4);
            mkb = (mv.x ? 1u : 0u) | (mv.y ? 0x100u : 0u)
                | (mv.z ? 0x10000u : 0u) | (mv.w ? 0x1000000u : 0u);
        }
        ushortx4 o;
        o[0] = (mkb & 0x000000FFu) ? 0xFF80u : f2bf(pd.x);
        o[1] = (mkb & 0x0000FF00u) ? 0xFF80u : f2bf(pd.y);
        o[2] = (mkb & 0x00FF0000u) ? 0xFF80u : f2bf(pd.z);
        o[3] = (mkb & 0xFF000000u) ? 0xFF80u : f2bf(pd.w);
        *(ushortx4*)&pre[0][lr][lc * 4] = o;
    }
    __syncthreads();

    const float* kbase = k + ((size_t)(b * SEQ)) * CH + h * DH;
    const float* vbase = v + ((size_t)(b * SEQ)) * CH + h * DH;

    // ---- Fused pass: stream dis/mask (1-deep prefetch) + QK^T + exp ----
    float psum[4] = {0.f, 0.f, 0.f, 0.f};
    for (int mc = 0; mc < 8; ++mc) {
        // prefetch chunk mc+1 (issued first: HBM latency covered by chunk mc)
        float4 pdn; unsigned pmn = 0; int4 pm32n;
        const int cb = (mc + 1) * 128 + lc * 4;
        if (mc < 7) {
            pdn = *(const float4*)(disrow + cb);
            if (fl) pmn = *(const unsigned*)(m8r + cb);
            else    pm32n = *(const int4*)(m32r + cb);
        }
        // K rows (L2) + MFMA for chunk mc
        const int mg = mc * 128 + w * 16 + ln;
        const float* krow = kbase + (size_t)mg * CH;
        float4 k0 = *(const float4*)(krow + qd * 8);
        float4 k1 = *(const float4*)(krow + qd * 8 + 4);
        float4 k2 = *(const float4*)(krow + 32 + qd * 8);
        float4 k3 = *(const float4*)(krow + 32 + qd * 8 + 4);
        shortx8 b0 = pack8(k0, k1), b1 = pack8(k2, k3);
        floatx4 acc = {0.f, 0.f, 0.f, 0.f};
        acc = __builtin_amdgcn_mfma_f32_16x16x32_bf16(aq0, b0, acc, 0, 0, 0);
        acc = __builtin_amdgcn_mfma_f32_16x16x32_bf16(aq1, b1, acc, 0, 0, 0);
        const int colw = w * 16 + ln;
        #pragma unroll
        for (int r = 0; r < 4; ++r) {                 // D: col=ln, row=qd*4+r
            float pv = bf2f(pre[mc & 1][qd * 4 + r][colw]);  // -inf if masked
            float ex = __expf((acc[r] + pv) * 0.125f);
            psum[r] += ex;
            Sraw[qd * 4 + r][mg] = f2bf(ex);
        }
        // stage prefetched chunk into the other buffer
        if (mc < 7) {
            unsigned mkb;
            if (fl) mkb = pmn;
            else mkb = (pm32n.x ? 1u : 0u) | (pm32n.y ? 0x100u : 0u)
                     | (pm32n.z ? 0x10000u : 0u) | (pm32n.w ? 0x1000000u : 0u);
            ushortx4 o;
            o[0] = (mkb & 0x000000FFu) ? 0xFF80u : f2bf(pdn.x);
            o[1] = (mkb & 0x0000FF00u) ? 0xFF80u : f2bf(pdn.y);
            o[2] = (mkb & 0x00FF0000u) ? 0xFF80u : f2bf(pdn.z);
            o[3] = (mkb & 0xFF000000u) ? 0xFF80u : f2bf(pdn.w);
            *(ushortx4*)&pre[(mc + 1) & 1][lr][lc * 4] = o;
        }
        __syncthreads();
    }

    // per-wave row sums: reduce over the 16 ln-lanes of each qd group
    #pragma unroll
    for (int r = 0; r < 4; ++r) {
        float s = psum[r];
        #pragma unroll
        for (int m = 8; m; m >>= 1) s += __shfl_xor(s, m, 16);
        if (ln == 0) part[w][qd * 4 + r] = s;
    }
    __syncthreads();

    if (t < RB) {
        float s = 0.f;
        #pragma unroll
        for (int j = 0; j < 8; ++j) s += part[j][t];
        invs[t] = 1.0f / s;
    }
    __syncthreads();

    // ---- Pass 3: O = (E V) * inv, fused with p_attn row writes ----
    const int hm = w >> 2;            // m-half 0/1
    const int c  = (w & 3) * 16;      // output col slice
    float* prow = pout + ((size_t)((h * BATCH + b) * SEQ + n0)) * SEQ;
    floatx4 acco = {0.f, 0.f, 0.f, 0.f};
    for (int st = 0; st < 16; ++st) {
        const int kb = hm * 512 + st * 32 + qd * 8;
        float vv[8];                               // V col gather (L2)
        #pragma unroll
        for (int j = 0; j < 8; ++j)
            vv[j] = vbase[(size_t)(kb + j) * CH + c + ln];
        // p_attn row st (independent of the gathers; overlaps their latency)
        {
            const float inv = invs[st];
            unsigned pk = *(const unsigned*)&Sraw[st][t * 2];
            float2 pv = { bf2f((unsigned short)(pk & 0xFFFFu)) * inv,
                          bf2f((unsigned short)(pk >> 16)) * inv };
            *(float2*)(prow + (size_t)st * SEQ + t * 2) = pv;
        }
        shortx8 af = *(const shortx8*)&Sraw[ln][kb];  // A[m=ln][k]
        shortx8 bfv;
        #pragma unroll
        for (int j = 0; j < 8; ++j) bfv[j] = (short)f2bf(vv[j]);
        acco = __builtin_amdgcn_mfma_f32_16x16x32_bf16(af, bfv, acco, 0, 0, 0);
    }
    if (hm == 1) {
        #pragma unroll
        for (int r = 0; r < 4; ++r) Opart[qd * 4 + r][c + ln] = acco[r];
    }
    __syncthreads();
    if (hm == 0) {
        #pragma unroll
        for (int r = 0; r < 4; ++r) {
            int row = qd * 4 + r;
            out[((size_t)(b * SEQ + n0 + row)) * CH + h * DH + c + ln]
                = (acco[r] + Opart[row][c + ln]) * invs[row];
        }
    }
}

extern "C" void kernel_launch(void* const* d_in, const int* in_sizes, int n_in,
                              void* d_out, int out_size, void* d_ws, size_t ws_size,
                              hipStream_t stream) {
    const float* q    = (const float*)d_in[0];
    const float* k    = (const float*)d_in[1];
    const float* v    = (const float*)d_in[2];
    const void*  mask = d_in[3];
    const float* dis  = (const float*)d_in[4];
    float* out  = (float*)d_out;
    float* pout = out + (size_t)BATCH * SEQ * CH;   // p_attn after out
    (void)d_ws; (void)ws_size;

    attn_mfma<<<HEADS * BATCH * (SEQ / RB), NTHR, 0, stream>>>(
        q, k, v, mask, dis, out, pout);
}